// Round 5
// baseline (554.208 us; speedup 1.0000x reference)
//
#include <hip/hip_runtime.h>
#include <hip/hip_bf16.h>

typedef __hip_bfloat16 bf16;
typedef unsigned short ushort_t;
typedef __attribute__((ext_vector_type(8))) short short8;
typedef __attribute__((ext_vector_type(4))) float f32x4;

#define NN 100000   // nodes
#define NE 640000   // edges
#define HD 128      // hidden
#define NB ((NN + 255) / 256)   // 391 scan blocks
#define LDA 136     // padded LDS row (bf16 elems): 68 words -> 2-way aliasing (free)

// flags[a]: 1 if float-array a is stored as f32, 0 if bf16.
// a: 0=node_emb 1=type_emb 2=len_emb 3=lane_emb 4=W(+b) 5=adj_val
__device__ __forceinline__ float ldmix(const void* p, size_t i, int f32) {
    return f32 ? ((const float*)p)[i]
               : __bfloat162float(((const bf16*)p)[i]);
}
__device__ __forceinline__ int allf32(const int* flags) {
    return flags[0] & flags[1] & flags[2] & flags[3] & flags[4] & flags[5];
}
__device__ __forceinline__ float bf2f(ushort_t u) {
    unsigned v = (unsigned)u << 16;
    return __builtin_bit_cast(float, v);
}
__device__ __forceinline__ ushort_t f2bf(float f) {
    bf16 h = __float2bfloat16(f);
    return *(ushort_t*)&h;
}

// Per-array dtype sniffing: real bf16 data here has |v| < 1 (exp <= 126).
// f32 bits misread as bf16 halves have exponent >= 130 with p ~ 0.5/word.
__global__ __launch_bounds__(256) void detect_kernel(
        const void* node_emb, const void* type_emb, const void* len_emb,
        const void* lane_emb, const void* W, const void* adj_val,
        int* __restrict__ flags) {
    __shared__ int found;
    const int a = blockIdx.x;  // 0..5
    const unsigned short* p;
    int n;
    switch (a) {
        case 0: p = (const unsigned short*)node_emb; n = 100000 * 64; break;
        case 1: p = (const unsigned short*)type_emb; n = 20 * 32;     break;
        case 2: p = (const unsigned short*)len_emb;  n = 100 * 16;    break;
        case 3: p = (const unsigned short*)lane_emb; n = 10 * 16;     break;
        case 4: p = (const unsigned short*)W;        n = HD * HD;     break;
        default: p = (const unsigned short*)adj_val; n = NE;          break;
    }
    if (n > 16384) n = 16384;
    if (threadIdx.x == 0) found = 0;
    __syncthreads();
    int loc = 0;
    for (int i = threadIdx.x; i < n; i += 256) {
        int e = (p[i] >> 7) & 0xFF;
        if (e >= 130) loc = 1;
    }
    if (loc) atomicOr(&found, 1);
    __syncthreads();
    if (threadIdx.x == 0) flags[a] = found;
}

// x[i,:] = concat(lane[16], type[32], length[16], node[64]); stored bf16
// (identical math to staging-time rounding) unless all-f32 hedge mode.
__global__ __launch_bounds__(256) void embed_kernel(const int* __restrict__ nodef,
        const int* __restrict__ typef, const int* __restrict__ lenf,
        const int* __restrict__ lanef,
        const void* __restrict__ node_emb, const void* __restrict__ type_emb,
        const void* __restrict__ len_emb, const void* __restrict__ lane_emb,
        const int* __restrict__ flags, void* __restrict__ x) {
    int idx = blockIdx.x * 256 + threadIdx.x;   // grid exactly NN*64
    int i = idx >> 6;
    int c = (idx & 63) * 2;   // column pair; table boundaries (16,48,64) are even
    float v0, v1;
    if (c < 16) {
        size_t o = (size_t)lanef[i] * 16 + c;
        v0 = ldmix(lane_emb, o, flags[3]); v1 = ldmix(lane_emb, o + 1, flags[3]);
    } else if (c < 48) {
        size_t o = (size_t)typef[i] * 32 + (c - 16);
        v0 = ldmix(type_emb, o, flags[1]); v1 = ldmix(type_emb, o + 1, flags[1]);
    } else if (c < 64) {
        size_t o = (size_t)lenf[i] * 16 + (c - 48);
        v0 = ldmix(len_emb, o, flags[2]); v1 = ldmix(len_emb, o + 1, flags[2]);
    } else {
        size_t o = (size_t)nodef[i] * 64 + (c - 64);
        v0 = ldmix(node_emb, o, flags[0]); v1 = ldmix(node_emb, o + 1, flags[0]);
    }
    const size_t o = (size_t)i * HD + c;
    if (!allf32(flags)) {
        ushort2 u; u.x = f2bf(v0); u.y = f2bf(v1);
        *(ushort2*)((ushort_t*)x + o) = u;
    } else {
        float2 f; f.x = v0; f.y = v1;
        *(float2*)((float*)x + o) = f;
    }
}

// ---- CSR build ----

__global__ __launch_bounds__(256) void hist_kernel(const int* __restrict__ dst,
                                                   int* __restrict__ cnt) {
    int e = blockIdx.x * 256 + threadIdx.x;   // grid exactly NE
    atomicAdd(&cnt[dst[e]], 1);
}

__global__ __launch_bounds__(256) void scan1_kernel(const int* __restrict__ cnt,
                                                    int* __restrict__ bsum) {
    int idx = blockIdx.x * 256 + threadIdx.x;
    int v = (idx < NN) ? cnt[idx] : 0;
    for (int o = 32; o; o >>= 1) v += __shfl_down(v, o, 64);
    __shared__ int ws_[4];
    if ((threadIdx.x & 63) == 0) ws_[threadIdx.x >> 6] = v;
    __syncthreads();
    if (threadIdx.x == 0) bsum[blockIdx.x] = ws_[0] + ws_[1] + ws_[2] + ws_[3];
}

__global__ __launch_bounds__(512) void scan2_kernel(const int* __restrict__ bsum,
                                                    int* __restrict__ boff) {
    __shared__ int s[512];
    int t = threadIdx.x;
    int v = (t < NB) ? bsum[t] : 0;
    s[t] = v;
    __syncthreads();
    for (int o = 1; o < 512; o <<= 1) {
        int u = (t >= o) ? s[t - o] : 0;
        __syncthreads();
        s[t] += u;
        __syncthreads();
    }
    if (t < NB) boff[t] = s[t] - v;
}

__global__ __launch_bounds__(256) void scan3_kernel(const int* __restrict__ cnt,
        const int* __restrict__ boff, int* __restrict__ offs, int* __restrict__ pos) {
    __shared__ int s[256];
    int idx = blockIdx.x * 256 + threadIdx.x;
    int t = threadIdx.x;
    int v = (idx < NN) ? cnt[idx] : 0;
    s[t] = v;
    __syncthreads();
    for (int o = 1; o < 256; o <<= 1) {
        int u = (t >= o) ? s[t - o] : 0;
        __syncthreads();
        s[t] += u;
        __syncthreads();
    }
    int excl = s[t] - v + boff[blockIdx.x];
    if (idx <= NN) {
        offs[idx] = excl;
        if (idx < NN) pos[idx] = excl;
    }
}

__global__ __launch_bounds__(256) void position_kernel(const int* __restrict__ src,
        const int* __restrict__ dst, const void* __restrict__ val,
        const int* __restrict__ flags, int* __restrict__ pos,
        int* __restrict__ esrc, float* __restrict__ eval) {
    int e = blockIdx.x * 256 + threadIdx.x;   // grid exactly NE
    int d = dst[e];
    int slot = atomicAdd(&pos[d], 1);
    esrc[slot] = src[e];
    eval[slot] = ldmix(val, e, flags[5]);
}

// W -> Wt[n][k] bf16 (pre-transposed so MFMA B-frags are contiguous ds_read_b128)
__global__ __launch_bounds__(256) void prep_kernel(const void* __restrict__ W,
        const int* __restrict__ flags, ushort_t* __restrict__ Wt) {
    int idx = blockIdx.x * 256 + threadIdx.x;   // grid 64 -> 16384
    int n = idx >> 7;
    int k = idx & 127;
    Wt[idx] = f2bf(ldmix(W, (size_t)k * HD + n, flags[4]));
}

// ---- per-layer kernels ----

// SUP = X @ W via mfma_f32_16x16x32_bf16. 256 thr = 4 waves, 64 rows/block.
// Wave w computes cols [w*32, w*32+32). A[m=lane&15][k=quad*8+j];
// B[k][n=lane&15]; C/D: col=lane&15, row=quad*4+reg.
__global__ __launch_bounds__(256) void gemm_kernel(const void* __restrict__ X,
        const ushort_t* __restrict__ Wt, const int* __restrict__ flags,
        void* __restrict__ sup, int sup_tier_bf) {
    __shared__ ushort_t Xs[64 * LDA];    // 17.0 KB
    __shared__ ushort_t Ws[128 * LDA];   // 34.0 KB
    const int tid = threadIdx.x;
    const int row0 = blockIdx.x * 64;
    const int of32 = allf32(flags);

    if (!of32) {
        const ushort_t* Xb = (const ushort_t*)X;
#pragma unroll
        for (int i = 0; i < 4; ++i) {
            int chunk = i * 256 + tid;      // 0..1023
            int m = chunk >> 4;             // 0..63
            int c8 = (chunk & 15) * 8;
            int gm = row0 + m;
            if (gm >= NN) gm = NN - 1;
            *(uint4*)&Xs[m * LDA + c8] = *(const uint4*)&Xb[(size_t)gm * HD + c8];
        }
    } else {
        const float* Xf = (const float*)X;
#pragma unroll
        for (int i = 0; i < 8; ++i) {
            int chunk = i * 256 + tid;      // 0..2047
            int m = chunk >> 5;
            int c4 = (chunk & 31) * 4;
            int gm = row0 + m;
            if (gm >= NN) gm = NN - 1;
            const float4 xv = *(const float4*)&Xf[(size_t)gm * HD + c4];
            ushort4 uv;
            uv.x = f2bf(xv.x); uv.y = f2bf(xv.y); uv.z = f2bf(xv.z); uv.w = f2bf(xv.w);
            *(ushort4*)&Xs[m * LDA + c4] = uv;
        }
    }
#pragma unroll
    for (int i = 0; i < 8; ++i) {
        int chunk = i * 256 + tid;          // 0..2047
        int n = chunk >> 4;
        int k8 = (chunk & 15) * 8;
        *(uint4*)&Ws[n * LDA + k8] = *(const uint4*)&Wt[n * HD + k8];
    }
    __syncthreads();

    const int w = tid >> 6;
    const int lane = tid & 63;
    const int ln = lane & 15;
    const int quad = lane >> 4;
    const int koff = quad * 8;

    short8 bfrg[2][4];
#pragma unroll
    for (int nt = 0; nt < 2; ++nt)
#pragma unroll
        for (int kc = 0; kc < 4; ++kc)
            bfrg[nt][kc] = *(const short8*)&Ws[(w * 32 + nt * 16 + ln) * LDA + kc * 32 + koff];

    f32x4 acc[4][2];
    const f32x4 zero = {0.f, 0.f, 0.f, 0.f};
#pragma unroll
    for (int mt = 0; mt < 4; ++mt) { acc[mt][0] = zero; acc[mt][1] = zero; }

#pragma unroll
    for (int mt = 0; mt < 4; ++mt) {
        short8 afrg[4];
#pragma unroll
        for (int kc = 0; kc < 4; ++kc)
            afrg[kc] = *(const short8*)&Xs[(mt * 16 + ln) * LDA + kc * 32 + koff];
#pragma unroll
        for (int nt = 0; nt < 2; ++nt)
#pragma unroll
            for (int kc = 0; kc < 4; ++kc)
                acc[mt][nt] = __builtin_amdgcn_mfma_f32_16x16x32_bf16(
                        afrg[kc], bfrg[nt][kc], acc[mt][nt], 0, 0, 0);
    }

    const int sup_bf = sup_tier_bf | (!of32);
    if (!sup_bf) {
        float* sp = (float*)sup;
#pragma unroll
        for (int mt = 0; mt < 4; ++mt)
#pragma unroll
            for (int reg = 0; reg < 4; ++reg) {
                int gm = row0 + mt * 16 + quad * 4 + reg;
                if (gm < NN) {
#pragma unroll
                    for (int nt = 0; nt < 2; ++nt)
                        sp[(size_t)gm * HD + w * 32 + nt * 16 + ln] = acc[mt][nt][reg];
                }
            }
    } else {
        ushort_t* sp = (ushort_t*)sup;
#pragma unroll
        for (int mt = 0; mt < 4; ++mt)
#pragma unroll
            for (int reg = 0; reg < 4; ++reg) {
                int gm = row0 + mt * 16 + quad * 4 + reg;
                if (gm < NN) {
#pragma unroll
                    for (int nt = 0; nt < 2; ++nt)
                        sp[(size_t)gm * HD + w * 32 + nt * 16 + ln] = f2bf(acc[mt][nt][reg]);
                }
            }
    }
}

// Pull-mode aggregation: one wave per dst node, f32 accumulate.
// X[d,:] = b + sum_j eval[j] * SUP[esrc[j],:]; optional out write.
__global__ __launch_bounds__(256) void agg_kernel(const void* __restrict__ sup,
        int sup_tier_bf, const int* __restrict__ offs, const int* __restrict__ esrc,
        const float* __restrict__ eval, const void* __restrict__ b_,
        const int* __restrict__ flags, void* __restrict__ X,
        void* __restrict__ out, int write_out) {
    const int node = blockIdx.x * 4 + (threadIdx.x >> 6);   // grid exactly NN/4
    const int lane = threadIdx.x & 63;
    const int c = lane * 2;
    const int lo = offs[node];
    const int hi = offs[node + 1];
    const int of32 = allf32(flags);
    const int sup_bf = sup_tier_bf | (!of32);
    float2 acc = {0.f, 0.f};
    if (sup_bf) {
        const ushort_t* sp = (const ushort_t*)sup;
        for (int j = lo; j < hi; ++j) {
            const int s = esrc[j];
            const float v = eval[j];
            const ushort2 uv = *(const ushort2*)(sp + (size_t)s * HD + c);
            acc.x += bf2f(uv.x) * v;
            acc.y += bf2f(uv.y) * v;
        }
    } else {
        const float* sp = (const float*)sup;
        for (int j = lo; j < hi; ++j) {
            const int s = esrc[j];
            const float v = eval[j];
            const float2 sv = *(const float2*)(sp + (size_t)s * HD + c);
            acc.x += sv.x * v;
            acc.y += sv.y * v;
        }
    }
    acc.x += ldmix(b_, c, flags[4]);
    acc.y += ldmix(b_, c + 1, flags[4]);
    const size_t o = (size_t)node * HD + c;
    if (!of32) {
        ushort2 u; u.x = f2bf(acc.x); u.y = f2bf(acc.y);
        *(ushort2*)((ushort_t*)X + o) = u;
        if (write_out) *(ushort2*)((ushort_t*)out + o) = u;
    } else {
        float2 f; f.x = acc.x; f.y = acc.y;
        *(float2*)((float*)X + o) = f;
        if (write_out) *(float2*)((float*)out + o) = f;
    }
}

// fallback tier only (SUP aliased to d_out): final X -> out copy/cast
__global__ __launch_bounds__(256) void cast_kernel(const void* __restrict__ X,
        const int* __restrict__ flags, void* __restrict__ out) {
    int idx = blockIdx.x * 256 + threadIdx.x;   // grid exactly NN*HD
    if (!allf32(flags)) ((ushort_t*)out)[idx] = ((const ushort_t*)X)[idx];
    else                ((float*)out)[idx] = ((const float*)X)[idx];
}

extern "C" void kernel_launch(void* const* d_in, const int* in_sizes, int n_in,
                              void* d_out, int out_size, void* d_ws, size_t ws_size,
                              hipStream_t stream) {
    const int*  nodef    = (const int*)d_in[0];
    const int*  typef    = (const int*)d_in[1];
    const int*  lenf     = (const int*)d_in[2];
    const int*  lanef    = (const int*)d_in[3];
    const int*  adj_src  = (const int*)d_in[4];
    const int*  adj_dst  = (const int*)d_in[5];
    const void* adj_val  = d_in[6];
    const void* node_emb = d_in[7];
    const void* type_emb = d_in[8];
    const void* len_emb  = d_in[9];
    const void* lane_emb = d_in[10];
    const void* W        = d_in[11];
    const void* b        = d_in[12];

    // ws layout (chunks 16B-aligned); X/SUP reserved f32-sized for hedge mode
    const size_t xbytes = (size_t)NN * HD * sizeof(float);   // 51.2 MB
    char* wp = (char*)d_ws;
    int*      flags = (int*)wp;      wp += 256;
    void*     X     = (void*)wp;     wp += xbytes;
    int*      cnt   = (int*)wp;      wp += (size_t)NN * 4;
    int*      offs  = (int*)wp;      wp += 400016;            // NN+1 ints, padded
    int*      pos   = (int*)wp;      wp += (size_t)NN * 4;
    int*      esrc  = (int*)wp;      wp += (size_t)NE * 4;
    float*    eval  = (float*)wp;    wp += (size_t)NE * 4;
    ushort_t* Wt    = (ushort_t*)wp; wp += 32768;
    int*      bsum  = (int*)wp;      wp += 1600;
    int*      boff  = (int*)wp;      wp += 1600;
    const size_t used = (size_t)(wp - (char*)d_ws);

    void* SUP;
    int sup_tier_bf, sup_is_out;
    if (ws_size >= used + xbytes)          { SUP = wp;    sup_tier_bf = 0; sup_is_out = 0; }
    else if (ws_size >= used + xbytes / 2) { SUP = wp;    sup_tier_bf = 1; sup_is_out = 0; }
    else                                   { SUP = d_out; sup_tier_bf = 1; sup_is_out = 1; }

    detect_kernel<<<6, 256, 0, stream>>>(node_emb, type_emb, len_emb, lane_emb,
                                         W, adj_val, flags);
    embed_kernel<<<(NN * 64) / 256, 256, 0, stream>>>(nodef, typef, lenf, lanef,
            node_emb, type_emb, len_emb, lane_emb, flags, X);

    // CSR build (graph identical across layers)
    hipMemsetAsync(cnt, 0, (size_t)NN * 4, stream);
    hist_kernel<<<NE / 256, 256, 0, stream>>>(adj_dst, cnt);
    scan1_kernel<<<NB, 256, 0, stream>>>(cnt, bsum);
    scan2_kernel<<<1, 512, 0, stream>>>(bsum, boff);
    scan3_kernel<<<NB, 256, 0, stream>>>(cnt, boff, offs, pos);
    position_kernel<<<NE / 256, 256, 0, stream>>>(adj_src, adj_dst, adj_val,
                                                  flags, pos, esrc, eval);
    prep_kernel<<<64, 256, 0, stream>>>(W, flags, Wt);

    for (int l = 0; l < 3; ++l) {
        gemm_kernel<<<(NN + 63) / 64, 256, 0, stream>>>(X, Wt, flags, SUP, sup_tier_bf);
        const int wout = (l == 2 && !sup_is_out) ? 1 : 0;
        agg_kernel<<<NN / 4, 256, 0, stream>>>(SUP, sup_tier_bf, offs, esrc, eval,
                                               b, flags, X, d_out, wout);
    }
    if (sup_is_out)
        cast_kernel<<<(NN * HD) / 256, 256, 0, stream>>>(X, flags, d_out);
}

// Round 6
// 408.898 us; speedup vs baseline: 1.3554x; 1.3554x over previous
//
#include <hip/hip_runtime.h>
#include <hip/hip_bf16.h>

typedef __hip_bfloat16 bf16;
typedef unsigned short ushort_t;
typedef __attribute__((ext_vector_type(8))) short short8;
typedef __attribute__((ext_vector_type(4))) float f32x4;

#define NN 100000   // nodes
#define NE 640000   // edges
#define HD 128      // hidden
#define NB ((NN + 255) / 256)   // 391 scan blocks
#define LDA 136     // padded LDS row (bf16 elems): 68 words -> 2-way aliasing (free)

// flags[a]: 1 if float-array a is stored as f32, 0 if bf16 (input dtype sniffing).
// a: 0=node_emb 1=type_emb 2=len_emb 3=lane_emb 4=W(+b) 5=adj_val
// NOTE: internal X/SUP are ALWAYS bf16 regardless; flags only pick input load
// width and the final d_out dtype.
__device__ __forceinline__ float ldmix(const void* p, size_t i, int f32) {
    return f32 ? ((const float*)p)[i]
               : __bfloat162float(((const bf16*)p)[i]);
}
__device__ __forceinline__ int allf32(const int* flags) {
    return flags[0] & flags[1] & flags[2] & flags[3] & flags[4] & flags[5];
}
__device__ __forceinline__ float bf2f(ushort_t u) {
    unsigned v = (unsigned)u << 16;
    return __builtin_bit_cast(float, v);
}
__device__ __forceinline__ ushort_t f2bf(float f) {
    bf16 h = __float2bfloat16(f);
    return *(ushort_t*)&h;
}

// Per-array dtype sniffing: real bf16 data here has |v| < 1 (exp <= 126).
// f32 bits misread as bf16 halves have exponent >= 130 with p ~ 0.5/word.
__global__ __launch_bounds__(256) void detect_kernel(
        const void* node_emb, const void* type_emb, const void* len_emb,
        const void* lane_emb, const void* W, const void* adj_val,
        int* __restrict__ flags) {
    __shared__ int found;
    const int a = blockIdx.x;  // 0..5
    const unsigned short* p;
    int n;
    switch (a) {
        case 0: p = (const unsigned short*)node_emb; n = 100000 * 64; break;
        case 1: p = (const unsigned short*)type_emb; n = 20 * 32;     break;
        case 2: p = (const unsigned short*)len_emb;  n = 100 * 16;    break;
        case 3: p = (const unsigned short*)lane_emb; n = 10 * 16;     break;
        case 4: p = (const unsigned short*)W;        n = HD * HD;     break;
        default: p = (const unsigned short*)adj_val; n = NE;          break;
    }
    if (n > 16384) n = 16384;
    if (threadIdx.x == 0) found = 0;
    __syncthreads();
    int loc = 0;
    for (int i = threadIdx.x; i < n; i += 256) {
        int e = (p[i] >> 7) & 0xFF;
        if (e >= 130) loc = 1;
    }
    if (loc) atomicOr(&found, 1);
    __syncthreads();
    if (threadIdx.x == 0) flags[a] = found;
}

// X[i,:] = concat(lane[16], type[32], length[16], node[64]) -> bf16 always
// (identical math to round-4: gemm rounded X to bf16 at staging anyway).
__global__ __launch_bounds__(256) void embed_kernel(const int* __restrict__ nodef,
        const int* __restrict__ typef, const int* __restrict__ lenf,
        const int* __restrict__ lanef,
        const void* __restrict__ node_emb, const void* __restrict__ type_emb,
        const void* __restrict__ len_emb, const void* __restrict__ lane_emb,
        const int* __restrict__ flags, ushort_t* __restrict__ X) {
    int idx = blockIdx.x * 256 + threadIdx.x;   // grid exactly NN*64
    int i = idx >> 6;
    int c = (idx & 63) * 2;   // column pair; table boundaries (16,48,64) are even
    float v0, v1;
    if (c < 16) {
        size_t o = (size_t)lanef[i] * 16 + c;
        v0 = ldmix(lane_emb, o, flags[3]); v1 = ldmix(lane_emb, o + 1, flags[3]);
    } else if (c < 48) {
        size_t o = (size_t)typef[i] * 32 + (c - 16);
        v0 = ldmix(type_emb, o, flags[1]); v1 = ldmix(type_emb, o + 1, flags[1]);
    } else if (c < 64) {
        size_t o = (size_t)lenf[i] * 16 + (c - 48);
        v0 = ldmix(len_emb, o, flags[2]); v1 = ldmix(len_emb, o + 1, flags[2]);
    } else {
        size_t o = (size_t)nodef[i] * 64 + (c - 64);
        v0 = ldmix(node_emb, o, flags[0]); v1 = ldmix(node_emb, o + 1, flags[0]);
    }
    ushort2 u; u.x = f2bf(v0); u.y = f2bf(v1);
    *(ushort2*)(X + (size_t)i * HD + c) = u;
}

// ---- CSR build ----

__global__ __launch_bounds__(256) void hist_kernel(const int* __restrict__ dst,
                                                   int* __restrict__ cnt) {
    int e = blockIdx.x * 256 + threadIdx.x;   // grid exactly NE
    atomicAdd(&cnt[dst[e]], 1);
}

__global__ __launch_bounds__(256) void scan1_kernel(const int* __restrict__ cnt,
                                                    int* __restrict__ bsum) {
    int idx = blockIdx.x * 256 + threadIdx.x;
    int v = (idx < NN) ? cnt[idx] : 0;
    for (int o = 32; o; o >>= 1) v += __shfl_down(v, o, 64);
    __shared__ int ws_[4];
    if ((threadIdx.x & 63) == 0) ws_[threadIdx.x >> 6] = v;
    __syncthreads();
    if (threadIdx.x == 0) bsum[blockIdx.x] = ws_[0] + ws_[1] + ws_[2] + ws_[3];
}

__global__ __launch_bounds__(512) void scan2_kernel(const int* __restrict__ bsum,
                                                    int* __restrict__ boff) {
    __shared__ int s[512];
    int t = threadIdx.x;
    int v = (t < NB) ? bsum[t] : 0;
    s[t] = v;
    __syncthreads();
    for (int o = 1; o < 512; o <<= 1) {
        int u = (t >= o) ? s[t - o] : 0;
        __syncthreads();
        s[t] += u;
        __syncthreads();
    }
    if (t < NB) boff[t] = s[t] - v;
}

__global__ __launch_bounds__(256) void scan3_kernel(const int* __restrict__ cnt,
        const int* __restrict__ boff, int* __restrict__ offs, int* __restrict__ pos) {
    __shared__ int s[256];
    int idx = blockIdx.x * 256 + threadIdx.x;
    int t = threadIdx.x;
    int v = (idx < NN) ? cnt[idx] : 0;
    s[t] = v;
    __syncthreads();
    for (int o = 1; o < 256; o <<= 1) {
        int u = (t >= o) ? s[t - o] : 0;
        __syncthreads();
        s[t] += u;
        __syncthreads();
    }
    int excl = s[t] - v + boff[blockIdx.x];
    if (idx <= NN) {
        offs[idx] = excl;
        if (idx < NN) pos[idx] = excl;
    }
}

__global__ __launch_bounds__(256) void position_kernel(const int* __restrict__ src,
        const int* __restrict__ dst, const void* __restrict__ val,
        const int* __restrict__ flags, int* __restrict__ pos,
        int* __restrict__ esrc, float* __restrict__ eval) {
    int e = blockIdx.x * 256 + threadIdx.x;   // grid exactly NE
    int d = dst[e];
    int slot = atomicAdd(&pos[d], 1);
    esrc[slot] = src[e];
    eval[slot] = ldmix(val, e, flags[5]);
}

// W -> Wt[n][k] bf16 (pre-transposed so MFMA B-frags are contiguous ds_read_b128)
__global__ __launch_bounds__(256) void prep_kernel(const void* __restrict__ W,
        const int* __restrict__ flags, ushort_t* __restrict__ Wt) {
    int idx = blockIdx.x * 256 + threadIdx.x;   // grid 64 -> 16384
    int n = idx >> 7;
    int k = idx & 127;
    Wt[idx] = f2bf(ldmix(W, (size_t)k * HD + n, flags[4]));
}

// ---- per-layer kernels ----

// SUP = X @ W via mfma_f32_16x16x32_bf16. 256 thr = 4 waves, 64 rows/block.
// Wave w computes cols [w*32, w*32+32). A[m=lane&15][k=quad*8+j];
// B[k][n=lane&15]; C/D: col=lane&15, row=quad*4+reg.
__global__ __launch_bounds__(256) void gemm_kernel(const ushort_t* __restrict__ X,
        const ushort_t* __restrict__ Wt, ushort_t* __restrict__ sup) {
    __shared__ ushort_t Xs[64 * LDA];    // 17.0 KB
    __shared__ ushort_t Ws[128 * LDA];   // 34.0 KB
    const int tid = threadIdx.x;
    const int row0 = blockIdx.x * 64;

#pragma unroll
    for (int i = 0; i < 4; ++i) {
        int chunk = i * 256 + tid;      // 0..1023
        int m = chunk >> 4;             // 0..63
        int c8 = (chunk & 15) * 8;
        int gm = row0 + m;
        if (gm >= NN) gm = NN - 1;
        *(uint4*)&Xs[m * LDA + c8] = *(const uint4*)&X[(size_t)gm * HD + c8];
    }
#pragma unroll
    for (int i = 0; i < 8; ++i) {
        int chunk = i * 256 + tid;      // 0..2047
        int n = chunk >> 4;
        int k8 = (chunk & 15) * 8;
        *(uint4*)&Ws[n * LDA + k8] = *(const uint4*)&Wt[n * HD + k8];
    }
    __syncthreads();

    const int w = tid >> 6;
    const int lane = tid & 63;
    const int ln = lane & 15;
    const int quad = lane >> 4;
    const int koff = quad * 8;

    short8 bfrg[2][4];
#pragma unroll
    for (int nt = 0; nt < 2; ++nt)
#pragma unroll
        for (int kc = 0; kc < 4; ++kc)
            bfrg[nt][kc] = *(const short8*)&Ws[(w * 32 + nt * 16 + ln) * LDA + kc * 32 + koff];

    f32x4 acc[4][2];
    const f32x4 zero = {0.f, 0.f, 0.f, 0.f};
#pragma unroll
    for (int mt = 0; mt < 4; ++mt) { acc[mt][0] = zero; acc[mt][1] = zero; }

#pragma unroll
    for (int mt = 0; mt < 4; ++mt) {
        short8 afrg[4];
#pragma unroll
        for (int kc = 0; kc < 4; ++kc)
            afrg[kc] = *(const short8*)&Xs[(mt * 16 + ln) * LDA + kc * 32 + koff];
#pragma unroll
        for (int nt = 0; nt < 2; ++nt)
#pragma unroll
            for (int kc = 0; kc < 4; ++kc)
                acc[mt][nt] = __builtin_amdgcn_mfma_f32_16x16x32_bf16(
                        afrg[kc], bfrg[nt][kc], acc[mt][nt], 0, 0, 0);
    }

#pragma unroll
    for (int mt = 0; mt < 4; ++mt)
#pragma unroll
        for (int reg = 0; reg < 4; ++reg) {
            int gm = row0 + mt * 16 + quad * 4 + reg;
            if (gm < NN) {
#pragma unroll
                for (int nt = 0; nt < 2; ++nt)
                    sup[(size_t)gm * HD + w * 32 + nt * 16 + ln] = f2bf(acc[mt][nt][reg]);
            }
        }
}

// Pull-mode aggregation: one wave per dst node, f32 accumulate, bf16 X store.
// X[d,:] = b + sum_j eval[j] * SUP[esrc[j],:]; final layer also writes d_out
// in the detected output dtype.
__global__ __launch_bounds__(256) void agg_kernel(const ushort_t* __restrict__ sup,
        const int* __restrict__ offs, const int* __restrict__ esrc,
        const float* __restrict__ eval, const void* __restrict__ b_,
        const int* __restrict__ flags, ushort_t* __restrict__ X,
        void* __restrict__ out, int write_out) {
    // wave-uniform node id -> offs/esrc/eval addressing scalarizes
    const int node = __builtin_amdgcn_readfirstlane(
            blockIdx.x * 4 + (threadIdx.x >> 6));   // grid exactly NN/4
    const int lane = threadIdx.x & 63;
    const int c = lane * 2;
    const int lo = offs[node];
    const int hi = offs[node + 1];
    float2 a0 = {0.f, 0.f}, a1 = {0.f, 0.f};
    int j = lo;
    for (; j + 1 < hi; j += 2) {   // dual accumulators overlap the two gathers
        const int s0 = esrc[j], s1 = esrc[j + 1];
        const float v0 = eval[j], v1 = eval[j + 1];
        const ushort2 u0 = *(const ushort2*)(sup + (size_t)s0 * HD + c);
        const ushort2 u1 = *(const ushort2*)(sup + (size_t)s1 * HD + c);
        a0.x += bf2f(u0.x) * v0;  a0.y += bf2f(u0.y) * v0;
        a1.x += bf2f(u1.x) * v1;  a1.y += bf2f(u1.y) * v1;
    }
    if (j < hi) {
        const int s0 = esrc[j];
        const float v0 = eval[j];
        const ushort2 u0 = *(const ushort2*)(sup + (size_t)s0 * HD + c);
        a0.x += bf2f(u0.x) * v0;  a0.y += bf2f(u0.y) * v0;
    }
    float2 acc;
    acc.x = a0.x + a1.x + ldmix(b_, c, flags[4]);
    acc.y = a0.y + a1.y + ldmix(b_, c + 1, flags[4]);
    const size_t o = (size_t)node * HD + c;
    ushort2 u; u.x = f2bf(acc.x); u.y = f2bf(acc.y);
    *(ushort2*)(X + o) = u;
    if (write_out) {
        if (allf32(flags)) { float2 f; f.x = acc.x; f.y = acc.y;
                             *(float2*)((float*)out + o) = f; }
        else               { *(ushort2*)((ushort_t*)out + o) = u; }
    }
}

// fallback tier only (SUP aliased to d_out): final X -> out copy/convert
__global__ __launch_bounds__(256) void cast_kernel(const ushort_t* __restrict__ X,
        const int* __restrict__ flags, void* __restrict__ out) {
    int idx = blockIdx.x * 256 + threadIdx.x;   // grid exactly NN*HD
    ushort_t u = X[idx];
    if (allf32(flags)) ((float*)out)[idx] = bf2f(u);
    else               ((ushort_t*)out)[idx] = u;
}

extern "C" void kernel_launch(void* const* d_in, const int* in_sizes, int n_in,
                              void* d_out, int out_size, void* d_ws, size_t ws_size,
                              hipStream_t stream) {
    const int*  nodef    = (const int*)d_in[0];
    const int*  typef    = (const int*)d_in[1];
    const int*  lenf     = (const int*)d_in[2];
    const int*  lanef    = (const int*)d_in[3];
    const int*  adj_src  = (const int*)d_in[4];
    const int*  adj_dst  = (const int*)d_in[5];
    const void* adj_val  = d_in[6];
    const void* node_emb = d_in[7];
    const void* type_emb = d_in[8];
    const void* len_emb  = d_in[9];
    const void* lane_emb = d_in[10];
    const void* W        = d_in[11];
    const void* b        = d_in[12];

    // ws layout (chunks 16B-aligned); X/SUP internal bf16 always
    const size_t xbytes = (size_t)NN * HD * 2;   // 25.6 MB
    char* wp = (char*)d_ws;
    int*      flags = (int*)wp;      wp += 256;
    ushort_t* X     = (ushort_t*)wp; wp += xbytes;
    int*      cnt   = (int*)wp;      wp += (size_t)NN * 4;
    int*      offs  = (int*)wp;      wp += 400016;            // NN+1 ints, padded
    int*      pos   = (int*)wp;      wp += (size_t)NN * 4;
    int*      esrc  = (int*)wp;      wp += (size_t)NE * 4;
    float*    eval  = (float*)wp;    wp += (size_t)NE * 4;
    ushort_t* Wt    = (ushort_t*)wp; wp += 32768;
    int*      bsum  = (int*)wp;      wp += 1600;
    int*      boff  = (int*)wp;      wp += 1600;
    const size_t used = (size_t)(wp - (char*)d_ws);

    ushort_t* SUP;
    int sup_is_out;
    if (ws_size >= used + xbytes) { SUP = (ushort_t*)wp;  sup_is_out = 0; }
    else                          { SUP = (ushort_t*)d_out; sup_is_out = 1; }

    detect_kernel<<<6, 256, 0, stream>>>(node_emb, type_emb, len_emb, lane_emb,
                                         W, adj_val, flags);
    embed_kernel<<<(NN * 64) / 256, 256, 0, stream>>>(nodef, typef, lenf, lanef,
            node_emb, type_emb, len_emb, lane_emb, flags, X);

    // CSR build (graph identical across layers)
    hipMemsetAsync(cnt, 0, (size_t)NN * 4, stream);
    hist_kernel<<<NE / 256, 256, 0, stream>>>(adj_dst, cnt);
    scan1_kernel<<<NB, 256, 0, stream>>>(cnt, bsum);
    scan2_kernel<<<1, 512, 0, stream>>>(bsum, boff);
    scan3_kernel<<<NB, 256, 0, stream>>>(cnt, boff, offs, pos);
    position_kernel<<<NE / 256, 256, 0, stream>>>(adj_src, adj_dst, adj_val,
                                                  flags, pos, esrc, eval);
    prep_kernel<<<64, 256, 0, stream>>>(W, flags, Wt);

    for (int l = 0; l < 3; ++l) {
        gemm_kernel<<<(NN + 63) / 64, 256, 0, stream>>>(X, Wt, SUP);
        const int wout = (l == 2 && !sup_is_out) ? 1 : 0;
        agg_kernel<<<NN / 4, 256, 0, stream>>>(SUP, offs, esrc, eval,
                                               b, flags, X, d_out, wout);
    }
    if (sup_is_out)
        cast_kernel<<<(NN * HD) / 256, 256, 0, stream>>>(X, flags, d_out);
}